// Round 1
// baseline (297.004 us; speedup 1.0000x reference)
//
#include <hip/hip_runtime.h>
#include <hip/hip_bf16.h>

// Problem constants: B=4, S=4096, H=1024, NUM_LAYERS=20, EPS=1e-6
static constexpr int Mdim = 16384;   // B*S
static constexpr int Ndim = 1024;    // H (output 'o')
static constexpr int Kdim = 1024;    // H (contraction 'd')
static constexpr int NLAYERS = 20;

typedef __bf16 bf16x8 __attribute__((ext_vector_type(8)));
typedef float f32x4 __attribute__((ext_vector_type(4)));

__device__ __forceinline__ ushort f2bf(float f) {
    unsigned u = __builtin_bit_cast(unsigned, f);
    u = (u + 0x7fffu + ((u >> 16) & 1u)) >> 16;   // RNE
    return (ushort)u;
}

__device__ __forceinline__ void gl_lds16(const ushort* g, ushort* l) {
    __builtin_amdgcn_global_load_lds((__attribute__((address_space(1))) void*)g,
                                     (__attribute__((address_space(3))) void*)l,
                                     16, 0, 0);
}

// ---------------------------------------------------------------------------
// Kernel 1: w_sum over 20 layers, *(1/20), cast to bf16.  W layout [o][d].
// ---------------------------------------------------------------------------
__global__ __launch_bounds__(256) void wsum_kernel(const float* __restrict__ w,
                                                   ushort* __restrict__ wb) {
    size_t e = ((size_t)blockIdx.x * 256 + threadIdx.x) * 4;  // element offset
    float4 acc = make_float4(0.f, 0.f, 0.f, 0.f);
    for (int l = 0; l < NLAYERS; ++l) {
        float4 v = *(const float4*)&w[(size_t)l * (Ndim * Kdim) + e];
        acc.x += v.x; acc.y += v.y; acc.z += v.z; acc.w += v.w;
    }
    const float sc = 1.0f / (float)NLAYERS;
    ushort4 o;
    o.x = f2bf(acc.x * sc); o.y = f2bf(acc.y * sc);
    o.z = f2bf(acc.z * sc); o.w = f2bf(acc.w * sc);
    *(ushort4*)&wb[e] = o;
}

// ---------------------------------------------------------------------------
// Kernel 2: scaled-layerhack RMSNorm (one block = one row of H=1024)
//           + emit bf16 copy of x for the GEMM.
// Math: mean(concat(x,-x)) == 0 exactly, so
//   var = sumsq(x) / (max^2 * H);  out = x/max * rsqrt(var+eps) * weight
// ---------------------------------------------------------------------------
__global__ __launch_bounds__(256) void rms_kernel(const float* __restrict__ x,
                                                  const float* __restrict__ wgt,
                                                  float* __restrict__ out,
                                                  ushort* __restrict__ xb) {
    const size_t row = blockIdx.x;
    const int t = threadIdx.x;
    const float* xr = x + row * 1024;
    float4 v = *(const float4*)&xr[t * 4];

    float mx = fmaxf(fmaxf(fabsf(v.x), fabsf(v.y)), fmaxf(fabsf(v.z), fabsf(v.w)));
    float ss = v.x * v.x + v.y * v.y + v.z * v.z + v.w * v.w;
    #pragma unroll
    for (int off = 1; off < 64; off <<= 1) {
        mx = fmaxf(mx, __shfl_xor(mx, off));
        ss += __shfl_xor(ss, off);
    }
    __shared__ float sm[4], sv[4];
    const int w = t >> 6, l = t & 63;
    if (l == 0) { sm[w] = mx; sv[w] = ss; }
    __syncthreads();
    mx = fmaxf(fmaxf(sm[0], sm[1]), fmaxf(sm[2], sm[3]));
    ss = sv[0] + sv[1] + sv[2] + sv[3];

    mx = fmaxf(mx, 1e-6f);                       // clip
    float var = ss / (mx * mx * 1024.0f);
    float s = rsqrtf(var + 1e-6f) / mx;

    float4 wv = *(const float4*)&wgt[t * 4];
    float4 o;
    o.x = v.x * s * wv.x; o.y = v.y * s * wv.y;
    o.z = v.z * s * wv.z; o.w = v.w * s * wv.w;
    *(float4*)&out[row * 1024 + t * 4] = o;

    ushort4 ub;
    ub.x = f2bf(v.x); ub.y = f2bf(v.y); ub.z = f2bf(v.z); ub.w = f2bf(v.w);
    *(ushort4*)&xb[row * 1024 + t * 4] = ub;
}

// ---------------------------------------------------------------------------
// Kernel 3: bf16 GEMM  C[m][n] = sum_d X[m][d] * W[n][d]   (f32 out)
// m97 structure: 128x128 tile, BK=32, 4 waves (2x2), acc 4x4 of 16x16x32 MFMA,
// global_load_lds width=16 staging, 2 barriers per K-step.
// ---------------------------------------------------------------------------
__global__ __launch_bounds__(256) void gemm_kernel(const ushort* __restrict__ X,
                                                   const ushort* __restrict__ W,
                                                   float* __restrict__ C) {
    __shared__ __attribute__((aligned(16))) ushort ldsA[128 * 32];
    __shared__ __attribute__((aligned(16))) ushort ldsB[128 * 32];

    const int t = threadIdx.x;
    const int w = t >> 6, l = t & 63;
    const int m0 = blockIdx.y * 128;
    const int n0 = blockIdx.x * 128;
    const int wr = w >> 1, wc = w & 1;           // wave 2x2 grid, each 64x64 out

    f32x4 acc[4][4] = {};

    // staging: thread covers 8 bf16 (16B); 256 thr = 64 rows x 32 cols per issue
    const int srow = t >> 2;
    const int scol = (t & 3) * 8;
    const ushort* gA = X + (size_t)(m0 + srow) * Kdim + scol;
    const ushort* gB = W + (size_t)(n0 + srow) * Kdim + scol;
    ushort* lA = &ldsA[t * 8];
    ushort* lB = &ldsB[t * 8];

    // fragment addressing: lane holds row=(l&15), k = (l>>4)*8 .. +8
    const int frow = l & 15;
    const int fk = (l >> 4) * 8;

    for (int kt = 0; kt < Kdim; kt += 32) {
        gl_lds16(gA + kt, lA);
        gl_lds16(gA + kt + (size_t)64 * Kdim, lA + 2048);
        gl_lds16(gB + kt, lB);
        gl_lds16(gB + kt + (size_t)64 * Kdim, lB + 2048);
        __syncthreads();   // compiler emits vmcnt(0) drain before barrier

        bf16x8 a[4], b[4];
        #pragma unroll
        for (int i = 0; i < 4; ++i)
            a[i] = *(const bf16x8*)&ldsA[(wr * 64 + i * 16 + frow) * 32 + fk];
        #pragma unroll
        for (int i = 0; i < 4; ++i)
            b[i] = *(const bf16x8*)&ldsB[(wc * 64 + i * 16 + frow) * 32 + fk];
        #pragma unroll
        for (int i = 0; i < 4; ++i)
            #pragma unroll
            for (int j = 0; j < 4; ++j)
                acc[i][j] = __builtin_amdgcn_mfma_f32_16x16x32_bf16(a[i], b[j], acc[i][j], 0, 0, 0);
        __syncthreads();   // protect LDS before next-tile overwrite
    }

    // C/D layout (m89-verified): col = lane&15, row = (lane>>4)*4 + reg
    const int rbase = (l >> 4) * 4;
    const int ccol = l & 15;
    #pragma unroll
    for (int i = 0; i < 4; ++i)
        #pragma unroll
        for (int j = 0; j < 4; ++j) {
            size_t base = (size_t)(m0 + wr * 64 + i * 16 + rbase) * Ndim
                        + (n0 + wc * 64 + j * 16 + ccol);
            #pragma unroll
            for (int r = 0; r < 4; ++r)
                C[base + (size_t)r * Ndim] = acc[i][j][r];
        }
}

extern "C" void kernel_launch(void* const* d_in, const int* in_sizes, int n_in,
                              void* d_out, int out_size, void* d_ws, size_t ws_size,
                              hipStream_t stream) {
    const float* x  = (const float*)d_in[0];   // (4,4096,1024) f32
    const float* cw = (const float*)d_in[1];   // (20,1024,1024) f32
    const float* nw = (const float*)d_in[2];   // (1024,) f32

    float* rms_out  = (float*)d_out;                       // 16777216 f32
    float* conv_out = rms_out + (size_t)Mdim * Ndim;       // next 16777216 f32

    ushort* xb = (ushort*)d_ws;                            // 32 MB bf16 X
    ushort* wb = xb + (size_t)Mdim * Kdim;                 // 2 MB bf16 W_sum/20

    hipLaunchKernelGGL(wsum_kernel, dim3((Ndim * Kdim) / (256 * 4)), dim3(256), 0, stream,
                       cw, wb);
    hipLaunchKernelGGL(rms_kernel, dim3(Mdim), dim3(256), 0, stream,
                       x, nw, rms_out, xb);
    hipLaunchKernelGGL(gemm_kernel, dim3(Ndim / 128, Mdim / 128), dim3(256), 0, stream,
                       xb, wb, conv_out);
}

// Round 2
// 276.585 us; speedup vs baseline: 1.0738x; 1.0738x over previous
//
#include <hip/hip_runtime.h>
#include <hip/hip_bf16.h>

// Problem constants: B=4, S=4096, H=1024, NUM_LAYERS=20, EPS=1e-6
static constexpr int Mdim = 16384;   // B*S
static constexpr int Ndim = 1024;    // H (output 'o')
static constexpr int Kdim = 1024;    // H (contraction 'd')
static constexpr int NLAYERS = 20;
static constexpr int NT = Kdim / 64; // 16 K-tiles of BK=64

typedef __bf16 bf16x8 __attribute__((ext_vector_type(8)));
typedef float f32x4 __attribute__((ext_vector_type(4)));

__device__ __forceinline__ ushort f2bf(float f) {
    unsigned u = __builtin_bit_cast(unsigned, f);
    u = (u + 0x7fffu + ((u >> 16) & 1u)) >> 16;   // RNE
    return (ushort)u;
}

__device__ __forceinline__ void gl_lds16(const ushort* g, ushort* l) {
    __builtin_amdgcn_global_load_lds((__attribute__((address_space(1))) void*)g,
                                     (__attribute__((address_space(3))) void*)l,
                                     16, 0, 0);
}

// ---------------------------------------------------------------------------
// Kernel 1: w_sum over 20 layers, *(1/20), cast to bf16.  W layout [o][d].
// ---------------------------------------------------------------------------
__global__ __launch_bounds__(256) void wsum_kernel(const float* __restrict__ w,
                                                   ushort* __restrict__ wb) {
    size_t e = ((size_t)blockIdx.x * 256 + threadIdx.x) * 4;
    float4 acc = make_float4(0.f, 0.f, 0.f, 0.f);
    for (int l = 0; l < NLAYERS; ++l) {
        float4 v = *(const float4*)&w[(size_t)l * (Ndim * Kdim) + e];
        acc.x += v.x; acc.y += v.y; acc.z += v.z; acc.w += v.w;
    }
    const float sc = 1.0f / (float)NLAYERS;
    ushort4 o;
    o.x = f2bf(acc.x * sc); o.y = f2bf(acc.y * sc);
    o.z = f2bf(acc.z * sc); o.w = f2bf(acc.w * sc);
    *(ushort4*)&wb[e] = o;
}

// ---------------------------------------------------------------------------
// Kernel 2: scaled-layerhack RMSNorm (one block = one row of H=1024)
//           + emit bf16 copy of x for the GEMM.
// mean(concat(x,-x)) == 0 exactly -> var = sumsq/(max^2*H)
// ---------------------------------------------------------------------------
__global__ __launch_bounds__(256) void rms_kernel(const float* __restrict__ x,
                                                  const float* __restrict__ wgt,
                                                  float* __restrict__ out,
                                                  ushort* __restrict__ xb) {
    const size_t row = blockIdx.x;
    const int t = threadIdx.x;
    const float* xr = x + row * 1024;
    float4 v = *(const float4*)&xr[t * 4];

    float mx = fmaxf(fmaxf(fabsf(v.x), fabsf(v.y)), fmaxf(fabsf(v.z), fabsf(v.w)));
    float ss = v.x * v.x + v.y * v.y + v.z * v.z + v.w * v.w;
    #pragma unroll
    for (int off = 1; off < 64; off <<= 1) {
        mx = fmaxf(mx, __shfl_xor(mx, off));
        ss += __shfl_xor(ss, off);
    }
    __shared__ float sm[4], sv[4];
    const int w = t >> 6, l = t & 63;
    if (l == 0) { sm[w] = mx; sv[w] = ss; }
    __syncthreads();
    mx = fmaxf(fmaxf(sm[0], sm[1]), fmaxf(sm[2], sm[3]));
    ss = sv[0] + sv[1] + sv[2] + sv[3];

    mx = fmaxf(mx, 1e-6f);
    float var = ss / (mx * mx * 1024.0f);
    float s = rsqrtf(var + 1e-6f) / mx;

    float4 wv = *(const float4*)&wgt[t * 4];
    float4 o;
    o.x = v.x * s * wv.x; o.y = v.y * s * wv.y;
    o.z = v.z * s * wv.z; o.w = v.w * s * wv.w;
    *(float4*)&out[row * 1024 + t * 4] = o;

    ushort4 ub;
    ub.x = f2bf(v.x); ub.y = f2bf(v.y); ub.z = f2bf(v.z); ub.w = f2bf(v.w);
    *(ushort4*)&xb[row * 1024 + t * 4] = ub;
}

// ---------------------------------------------------------------------------
// Kernel 3: bf16 GEMM, 256x256 tile, BK=64, 8-phase schedule (m201 template).
//   C[m][n] = sum_d X[m][d] * W[n][d], f32 out.
//   8 waves (2M x 4N), per-wave out 128x64. LDS 128KiB = 2 buf x (A 32K + B 32K).
//   Half-tile stream order A0,A1,B0,B1; lead-7 stagger; boundary vmcnt(6).
//   LDS swizzle: byte ^= (row&7)<<4, applied on global SOURCE (linear gl_lds
//   dest) and on the ds_read address (rule #21: both-sides-or-neither).
// ---------------------------------------------------------------------------
__global__ __launch_bounds__(512, 2) void gemm8_kernel(const ushort* __restrict__ X,
                                                       const ushort* __restrict__ W,
                                                       float* __restrict__ C) {
    __shared__ __attribute__((aligned(16))) ushort lds[65536];  // 128 KiB
    const char* ldsc = (const char*)lds;

    const int tid = threadIdx.x;
    const int w = tid >> 6, l = tid & 63;
    const int wm = w >> 2, wn = w & 3;

    // XCD-chunked swizzle: 256 blocks, 8 XCDs, 32 blocks/XCD; same-M-row
    // blocks (sharing an A-panel) land on the same XCD for L2 reuse.
    const int bid = blockIdx.x;
    const int swz = (bid & 7) * 32 + (bid >> 3);
    const int m0 = (swz >> 2) * 256;
    const int n0 = (swz & 3) * 256;

    // ---- staging constants: thread covers 16B; 512 thr = 64 rows x 128B/issue
    const int srow = tid >> 3;                         // row within 64-row chunk
    const int scol = 8 * ((tid & 7) ^ (srow & 7));     // inverse-swizzled source col (elems)
    const ushort* gA = X + (size_t)(m0 + srow) * Kdim + scol;
    const ushort* gB = W + (size_t)(n0 + srow) * Kdim + scol;

    // half-tile j: jt=j>>2 (K-tile), r=j&3 (0:A0,1:A1,2:B0,3:B1), buf=jt&1
    auto STAGE = [&](int j) {
        if (j >= 4 * NT) return;
        const int jt = j >> 2, r = j & 3;
        const ushort* src = ((r & 2) ? gB : gA) + (size_t)(r & 1) * (128 * Kdim) + jt * 64;
        ushort* dst = lds + (jt & 1) * 32768 + r * 8192 + tid * 8;
        gl_lds16(src, dst);                 // chunk 0: rows 0-63 of half-tile
        gl_lds16(src + 64 * Kdim, dst + 4096);  // chunk 1: rows 64-127
    };

    // ---- per-lane fragment read bases (bytes, pre-swizzled)
    const int swzl = (l & 7) << 4;
    const int colp = ((l >> 4) * 16) ^ swzl;           // ks=0 col bytes; ks=1 = ^64
    const int abase = wm * 16384 + (l & 15) * 128 + colp;
    const int bbase = 32768 + (wn >> 1) * 16384 + ((wn & 1) * 64 + (l & 15)) * 128 + colp;

    f32x4 acc[8][4] = {};
    bf16x8 a0[4][2], a1[4][2], bfr[2][2];

    // ---- prologue: tile0 (4 half-tiles) + 3 half-tiles of tile1
    STAGE(0); STAGE(1); STAGE(2); STAGE(3);
    asm volatile("s_waitcnt vmcnt(4)" ::: "memory");
    STAGE(4); STAGE(5); STAGE(6);
    asm volatile("s_waitcnt vmcnt(6)" ::: "memory");   // tile0 fully landed
    __builtin_amdgcn_s_barrier();

#define LOAD_A(aset, mh_)                                                    \
    _Pragma("unroll") for (int mf = 0; mf < 4; ++mf) {                       \
        const int ad = bufb + abase + (mh_) * 8192 + mf * 2048;              \
        aset[mf][0] = *(const bf16x8*)(ldsc + ad);                           \
        aset[mf][1] = *(const bf16x8*)(ldsc + (ad ^ 64));                    \
    }
#define LOAD_B(nh_)                                                          \
    _Pragma("unroll") for (int nf = 0; nf < 2; ++nf) {                       \
        const int bd = bufb + bbase + (nh_) * 4096 + nf * 2048;              \
        bfr[nf][0] = *(const bf16x8*)(ldsc + bd);                            \
        bfr[nf][1] = *(const bf16x8*)(ldsc + (bd ^ 64));                     \
    }
#define MFMA_Q(aset, mh_, nh_)                                               \
    __builtin_amdgcn_s_setprio(1);                                           \
    _Pragma("unroll") for (int mf = 0; mf < 4; ++mf)                         \
        _Pragma("unroll") for (int nf = 0; nf < 2; ++nf) {                   \
            acc[(mh_) * 4 + mf][(nh_) * 2 + nf] =                            \
                __builtin_amdgcn_mfma_f32_16x16x32_bf16(aset[mf][0], bfr[nf][0], \
                    acc[(mh_) * 4 + mf][(nh_) * 2 + nf], 0, 0, 0);           \
            acc[(mh_) * 4 + mf][(nh_) * 2 + nf] =                            \
                __builtin_amdgcn_mfma_f32_16x16x32_bf16(aset[mf][1], bfr[nf][1], \
                    acc[(mh_) * 4 + mf][(nh_) * 2 + nf], 0, 0, 0);           \
        }                                                                    \
    __builtin_amdgcn_s_setprio(0);

    #pragma unroll 2
    for (int kt = 0; kt < NT; ++kt) {
        const int bufb = (kt & 1) * 65536;
        // phase 0: quadrant (0,0) — reads A0,B0 regions; issues next-buf B1
        LOAD_A(a0, 0);
        LOAD_B(0);
        STAGE(4 * kt + 7);
        __builtin_amdgcn_s_barrier();
        MFMA_Q(a0, 0, 0);
        __builtin_amdgcn_s_barrier();
        // phase 1: quadrant (1,0) — reads A1; overwrites cur A0 (done ph0)
        LOAD_A(a1, 1);
        STAGE(4 * kt + 8);
        __builtin_amdgcn_s_barrier();
        MFMA_Q(a1, 1, 0);
        __builtin_amdgcn_s_barrier();
        // phase 2: quadrant (0,1) — reads B1; overwrites cur A1 (done ph1)
        LOAD_B(1);
        STAGE(4 * kt + 9);
        __builtin_amdgcn_s_barrier();
        MFMA_Q(a0, 0, 1);
        __builtin_amdgcn_s_barrier();
        // phase 3: quadrant (1,1) — no ds; overwrites cur B0 (done ph1);
        // tile boundary: ensure next tile fully landed, keep 3 half-tiles in flight
        STAGE(4 * kt + 10);
        if (kt < NT - 2) asm volatile("s_waitcnt vmcnt(6)" ::: "memory");
        else             asm volatile("s_waitcnt vmcnt(0)" ::: "memory");
        __builtin_amdgcn_s_barrier();
        MFMA_Q(a1, 1, 1);
        __builtin_amdgcn_s_barrier();
    }
#undef LOAD_A
#undef LOAD_B
#undef MFMA_Q

    // ---- epilogue: C/D layout col=lane&15, row=(lane>>4)*4+reg (m89-verified)
    const int crow0 = m0 + wm * 128 + (l >> 4) * 4;
    const int ccol0 = n0 + wn * 64 + (l & 15);
    #pragma unroll
    for (int mh = 0; mh < 2; ++mh)
        #pragma unroll
        for (int mf = 0; mf < 4; ++mf)
            #pragma unroll
            for (int nh = 0; nh < 2; ++nh)
                #pragma unroll
                for (int nf = 0; nf < 2; ++nf) {
                    f32x4 v = acc[mh * 4 + mf][nh * 2 + nf];
                    size_t base = (size_t)(crow0 + mh * 64 + mf * 16) * Ndim
                                + (ccol0 + nh * 32 + nf * 16);
                    #pragma unroll
                    for (int r = 0; r < 4; ++r)
                        C[base + (size_t)r * Ndim] = v[r];
                }
}

extern "C" void kernel_launch(void* const* d_in, const int* in_sizes, int n_in,
                              void* d_out, int out_size, void* d_ws, size_t ws_size,
                              hipStream_t stream) {
    const float* x  = (const float*)d_in[0];   // (4,4096,1024) f32
    const float* cw = (const float*)d_in[1];   // (20,1024,1024) f32
    const float* nw = (const float*)d_in[2];   // (1024,) f32

    float* rms_out  = (float*)d_out;                       // 16777216 f32
    float* conv_out = rms_out + (size_t)Mdim * Ndim;       // next 16777216 f32

    ushort* xb = (ushort*)d_ws;                            // 32 MB bf16 X
    ushort* wb = xb + (size_t)Mdim * Kdim;                 // 2 MB bf16 W_sum/20

    hipLaunchKernelGGL(wsum_kernel, dim3((Ndim * Kdim) / (256 * 4)), dim3(256), 0, stream,
                       cw, wb);
    hipLaunchKernelGGL(rms_kernel, dim3(Mdim), dim3(256), 0, stream,
                       x, nw, rms_out, xb);
    hipLaunchKernelGGL(gemm8_kernel, dim3(256), dim3(512), 0, stream,
                       xb, wb, conv_out);
}